// Round 2
// baseline (502.127 us; speedup 1.0000x reference)
//
#include <hip/hip_runtime.h>

typedef unsigned short u16;
typedef unsigned int u32;
typedef short s8v __attribute__((ext_vector_type(8)));    // 8 bf16 (4 VGPRs)
typedef float f16v __attribute__((ext_vector_type(16)));  // 32x32 mfma acc

#define NHW 4096   // H*W
#define CIN 256    // C
#define CID 128    // CI (inter channels)
#define PB  524288 // per-batch frag elems (NHW*CID)

__device__ __forceinline__ u16 f2bf(float f) {
  union { float f; u32 u; } v; v.f = f;
  u32 r = v.u + 0x7fffu + ((v.u >> 16) & 1u);
  return (u16)(r >> 16);
}
__device__ __forceinline__ u32 pk2(float a, float b) {
  return (u32)f2bf(a) | ((u32)f2bf(b) << 16);
}
__device__ __forceinline__ int SIG(int reg, int h) {
  return (reg & 3) + 8 * (reg >> 2) + 4 * h;
}

// Frag-major layouts (per batch):
//  Qf/Kf[nblk128][ct4][hp2][lm32][r16] : value D(n = nblk*32+lm, ci-label(ct,hp,r))
//    attn reads qf[ks=2ct+hp] at lm*16 + h_attn*8  (k-label bijection over ci)
//  Vf[mblk128][ct4][ks2][hp2][lm32][j8]: V[m = mblk*32 + ks*16 + SIG(j,hp)][ci=ct*32+lm]
//  Of[nblk128][ks8][h2][lm32][j8]      : O[n=nblk*32+lm][ci = ks*16+h*8+j]  (plain)
//  Wf [p3][ct4][ksg16][h2][lm32][j8]   : W[ci=ct*32+lm][c = ksg*16+h*8+j] bf16
//  Wf2[ct8][ks8][h2][lm32][j8]         : W2[co=ct*32+lm][ci = ks*16+h*8+j] bf16

// ---------------------------------------------------------------------------
// Kernel 0: weight prep (bf16 frag-major) + BN fold.  grid=21, block=256.
// ---------------------------------------------------------------------------
__global__ __launch_bounds__(256) void wprep_kernel(
    const float* __restrict__ tw, const float* __restrict__ pw, const float* __restrict__ gw,
    const float* __restrict__ ww, const float* __restrict__ wb,
    const float* __restrict__ bg, const float* __restrict__ bb,
    const float* __restrict__ bm, const float* __restrict__ bv,
    u16* __restrict__ Wf, u16* __restrict__ Wf2,
    float* __restrict__ scl, float* __restrict__ offs)
{
  const int bid = blockIdx.x, t = threadIdx.x;
  const int lm = t & 31, h = (t >> 5) & 1, g4 = t >> 6;
  if (bid < 12) {
    const int p = bid >> 2, ct = bid & 3;
    const float* W = (p == 0) ? tw : (p == 1) ? pw : gw;
#pragma unroll
    for (int q = 0; q < 4; ++q) {
      const int ksg = g4 * 4 + q;
      const float* src = W + (size_t)(ct * 32 + lm) * 256 + ksg * 16 + h * 8;
      u32 pk[4];
#pragma unroll
      for (int e = 0; e < 4; ++e) pk[e] = pk2(src[2 * e], src[2 * e + 1]);
      *(uint4*)(Wf + p * 32768 + ct * 8192 + ksg * 512 + h * 256 + lm * 8) =
          make_uint4(pk[0], pk[1], pk[2], pk[3]);
    }
  } else if (bid < 20) {
    const int ct = bid - 12;
#pragma unroll
    for (int q = 0; q < 2; ++q) {
      const int ks = g4 * 2 + q;
      const float* src = ww + (size_t)(ct * 32 + lm) * 128 + ks * 16 + h * 8;
      u32 pk[4];
#pragma unroll
      for (int e = 0; e < 4; ++e) pk[e] = pk2(src[2 * e], src[2 * e + 1]);
      *(uint4*)(Wf2 + ct * 8192 + ks * 512 + h * 256 + lm * 8) =
          make_uint4(pk[0], pk[1], pk[2], pk[3]);
    }
  } else {
    float inv = bg[t] * __frsqrt_rn(bv[t] + 1e-5f);
    scl[t] = inv;
    offs[t] = (wb[t] - bm[t]) * inv + bb[t];
  }
}

// ---------------------------------------------------------------------------
// Kernel 1: MFMA projections.  grid=(NHW/64, B, 3), block=256 (4 waves).
// Per block: 64 n x 128 ci over 256 c.  Wave w: nt=w&1, ct-pair {2(w>>1),+1}.
// p<2: D = W·X  (A=W m=ci, B=X col=n) -> Qf/Kf sigma-layout.
// p=2: D = X·W  (A=X m=n,  B=W col=ci) -> Vf directly in PV B-frag form.
// X staged via XOR-swizzled LDS tile (64n x 64c bf16).
// ---------------------------------------------------------------------------
__global__ __launch_bounds__(256) void proj_kernel(
    const float* __restrict__ x, const float* __restrict__ y, const float* __restrict__ zz,
    const u16* __restrict__ Wf,
    const float* __restrict__ tb, const float* __restrict__ pb, const float* __restrict__ gb,
    u16* __restrict__ Qf, u16* __restrict__ Kf, u16* __restrict__ Vf)
{
  __shared__ __align__(16) u16 Xs[64 * 64];
  __shared__ float Bs[128];
  const int t = threadIdx.x;
  const int b = blockIdx.y, p = blockIdx.z;
  const int n0 = blockIdx.x * 64;
  const float* in  = (p == 0) ? x  : (p == 1) ? y  : zz;
  const float* Bv  = (p == 0) ? tb : (p == 1) ? pb : gb;
  u16*         out = (p == 0) ? Qf : (p == 1) ? Kf : Vf;
  const u16* Wfp = Wf + p * 32768;

  const int wave = t >> 6, lane = t & 63;
  const int lm = lane & 31, h = lane >> 5;
  const int nt = wave & 1, ctp = wave >> 1;
  const int cp = t >> 3, noct = t & 7;   // staging map: c-pair, n-oct

  if (t < 128) Bs[t] = Bv[t];

  u32* Xd = (u32*)Xs;
  const int nn = nt * 32 + lm;
  const int rmask = ((nn >> 3) & 7) << 2;

  f16v a0, a1;
#pragma unroll
  for (int r = 0; r < 16; ++r) { a0[r] = 0.f; a1[r] = 0.f; }

  float4 xr[4];
  {
    const float* basep = in + ((size_t)(b * CIN) + 2 * cp) * NHW + n0;
    xr[0] = *(const float4*)(basep + noct * 4);
    xr[1] = *(const float4*)(basep + 32 + noct * 4);
    xr[2] = *(const float4*)(basep + NHW + noct * 4);
    xr[3] = *(const float4*)(basep + NHW + 32 + noct * 4);
  }

  for (int ch = 0; ch < 4; ++ch) {
    __syncthreads();  // previous chunk consumed
    {
      const float* xa = (const float*)&xr[0];
      const float* xb = (const float*)&xr[1];
      const float* xc = (const float*)&xr[2];
      const float* xd = (const float*)&xr[3];
#pragma unroll
      for (int i = 0; i < 4; ++i) {
        int n1 = noct * 4 + i, n2 = n1 + 32;
        Xd[n1 * 32 + (cp ^ (((n1 >> 3) & 7) << 2))] = pk2(xa[i], xc[i]);
        Xd[n2 * 32 + (cp ^ (((n2 >> 3) & 7) << 2))] = pk2(xb[i], xd[i]);
      }
    }
    __syncthreads();
    if (ch < 3) {
      const float* basep = in + ((size_t)(b * CIN) + (ch + 1) * 64 + 2 * cp) * NHW + n0;
      xr[0] = *(const float4*)(basep + noct * 4);
      xr[1] = *(const float4*)(basep + 32 + noct * 4);
      xr[2] = *(const float4*)(basep + NHW + noct * 4);
      xr[3] = *(const float4*)(basep + NHW + 32 + noct * 4);
    }
    if (p < 2) {
#pragma unroll
      for (int ks = 0; ks < 4; ++ks) {
        s8v xf = *(const s8v*)(Xd + nn * 32 + ((ks * 8 + h * 4) ^ rmask));
        s8v w0 = *(const s8v*)(Wfp + (ctp * 2 + 0) * 8192 + (ch * 4 + ks) * 512 + h * 256 + lm * 8);
        s8v w1 = *(const s8v*)(Wfp + (ctp * 2 + 1) * 8192 + (ch * 4 + ks) * 512 + h * 256 + lm * 8);
        a0 = __builtin_amdgcn_mfma_f32_32x32x16_bf16(w0, xf, a0, 0, 0, 0);
        a1 = __builtin_amdgcn_mfma_f32_32x32x16_bf16(w1, xf, a1, 0, 0, 0);
      }
    } else {
#pragma unroll
      for (int ks = 0; ks < 4; ++ks) {
        s8v xf = *(const s8v*)(Xd + nn * 32 + ((ks * 8 + h * 4) ^ rmask));
        s8v w0 = *(const s8v*)(Wfp + (ctp * 2 + 0) * 8192 + (ch * 4 + ks) * 512 + h * 256 + lm * 8);
        s8v w1 = *(const s8v*)(Wfp + (ctp * 2 + 1) * 8192 + (ch * 4 + ks) * 512 + h * 256 + lm * 8);
        a0 = __builtin_amdgcn_mfma_f32_32x32x16_bf16(xf, w0, a0, 0, 0, 0);
        a1 = __builtin_amdgcn_mfma_f32_32x32x16_bf16(xf, w1, a1, 0, 0, 0);
      }
    }
  }

  // epilogue
  const size_t nblk = (size_t)blockIdx.x * 2 + nt;
  if (p < 2) {
    // lane (h,lm): n = n0+nt*32+lm, 16 ci = ct*32 + SIG(reg,h)
#pragma unroll
    for (int cti = 0; cti < 2; ++cti) {
      const int ct = ctp * 2 + cti;
      const f16v& ac = cti ? a1 : a0;
      float v[16];
#pragma unroll
      for (int reg = 0; reg < 16; ++reg) v[reg] = ac[reg] + Bs[ct * 32 + SIG(reg, h)];
      u32 pk[8];
#pragma unroll
      for (int e = 0; e < 8; ++e) pk[e] = pk2(v[2 * e], v[2 * e + 1]);
      u16* dst = out + (size_t)b * PB + nblk * 4096 + ct * 1024 + h * 512 + lm * 16;
      ((uint4*)dst)[0] = make_uint4(pk[0], pk[1], pk[2], pk[3]);
      ((uint4*)dst)[1] = make_uint4(pk[4], pk[5], pk[6], pk[7]);
    }
  } else {
    // lane (h,lm): ci = ct*32+lm, 16 n = nt*32 + SIG(reg,h); regs 0..7 -> ks=0, 8..15 -> ks=1
#pragma unroll
    for (int cti = 0; cti < 2; ++cti) {
      const int ct = ctp * 2 + cti;
      const f16v& ac = cti ? a1 : a0;
      const float bias = Bs[ct * 32 + lm];
      u32 pk[8];
#pragma unroll
      for (int e = 0; e < 8; ++e) pk[e] = pk2(ac[2 * e] + bias, ac[2 * e + 1] + bias);
      u16* dst = out + (size_t)b * PB + nblk * 4096 + ct * 1024 + h * 256 + lm * 8;
      *(uint4*)dst         = make_uint4(pk[0], pk[1], pk[2], pk[3]);
      *(uint4*)(dst + 512) = make_uint4(pk[4], pk[5], pk[6], pk[7]);
    }
  }
}

// ---------------------------------------------------------------------------
// Kernel 2: MFMA flash attention (sigma-relabeled ci; unnormalized exp).
// grid = 512 (1-D, XCD-swizzled), block = 512 = 8 waves; wave w: m-EIGHTH
// [w*512, +512) -> 16 jt iters.  2 blocks/CU x 8 waves = 4 waves/SIMD
// (2x occupancy vs 4-wave version; K/V traffic per block unchanged).
// XCD swizzle: lin%8 = XCD (dispatch round-robin); b = xcd>>1 so each XCD
// touches exactly ONE batch's K+V (2 MB) -> fully L2-resident (4 MB/XCD).
// Writes O bf16 frag-major (Of) for outproj.
// ---------------------------------------------------------------------------
__global__ __launch_bounds__(512, 4) void attn_kernel(
    const u16* __restrict__ Qf, const u16* __restrict__ Kf,
    const u16* __restrict__ Vf, u16* __restrict__ Of)
{
  __shared__ __align__(16) float Obuf[32][132];
  __shared__ float lbuf[32];
  const int t = threadIdx.x;
  const int wave = t >> 6, lane = t & 63;
  const int lm = lane & 31, half = lane >> 5;

  // XCD-aware decode: bijective over (b, nblk). 2 XCDs per batch.
  const int lin = blockIdx.x;
  const int xcd = lin & 7;
  const int b = xcd >> 1;
  const int nblk = ((xcd & 1) << 6) + (lin >> 3);

  // Q B-frags (k-label = sigma-relabeled ci; same labels as Kf -> S correct)
  s8v qf[8];
  {
    const u16* qp = Qf + (size_t)b * PB + (size_t)nblk * 4096 + lm * 16 + half * 8;
#pragma unroll
    for (int ks = 0; ks < 8; ++ks) qf[ks] = *(const s8v*)(qp + ks * 512);
  }

  const u16* Kb = Kf + (size_t)b * PB + lm * 16 + half * 8;
  const u16* Vb = Vf + (size_t)b * PB + half * 256 + lm * 8;
  const int mstart = wave * 512;

  f16v oacc[4];
#pragma unroll
  for (int c = 0; c < 4; ++c)
#pragma unroll
    for (int r = 0; r < 16; ++r) oacc[c][r] = 0.f;
  float lacc = 0.f;

  s8v kf[8];
  {
    const u16* kp = Kb + (size_t)mstart * 128;
#pragma unroll
    for (int ks = 0; ks < 8; ++ks) kf[ks] = *(const s8v*)(kp + ks * 512);
  }

  for (int jt = 0; jt < 16; ++jt) {
    const int m0 = mstart + jt * 32;

    s8v vf[8];
    {
      const u16* vp = Vb + (size_t)m0 * 128;
#pragma unroll
      for (int ct = 0; ct < 4; ++ct)
#pragma unroll
        for (int ks = 0; ks < 2; ++ks)
          vf[ct * 2 + ks] = *(const s8v*)(vp + ct * 1024 + ks * 512);
    }

    // Two independent 4-deep MFMA chains (halved dependency latency);
    // merged for free inside the exp argument below.
    f16v sacc0, sacc1;
#pragma unroll
    for (int r = 0; r < 16; ++r) { sacc0[r] = 0.f; sacc1[r] = 0.f; }
    __builtin_amdgcn_s_setprio(1);
#pragma unroll
    for (int ks = 0; ks < 4; ++ks) {
      sacc0 = __builtin_amdgcn_mfma_f32_32x32x16_bf16(kf[ks], qf[ks], sacc0, 0, 0, 0);
      sacc1 = __builtin_amdgcn_mfma_f32_32x32x16_bf16(kf[ks + 4], qf[ks + 4], sacc1, 0, 0, 0);
    }
    __builtin_amdgcn_s_setprio(0);

    {
      const u16* kp = Kb + (size_t)(m0 + 32) * 128;
#pragma unroll
      for (int ks = 0; ks < 8; ++ks) kf[ks] = *(const s8v*)(kp + ks * 512);
    }

    float pp0[8], pp1[8];
#pragma unroll
    for (int j = 0; j < 8; ++j) {
      float p0 = __expf(sacc0[j] + sacc1[j]);
      float p1 = __expf(sacc0[8 + j] + sacc1[8 + j]);
      lacc += p0 + p1;
      pp0[j] = p0;
      pp1[j] = p1;
    }
    // pack 2 f32 -> 2 bf16 per instruction (RNE, same as f2bf)
    union { s8v v; u32 w[4]; } pa0, pa1;
#pragma unroll
    for (int e = 0; e < 4; ++e) {
      u32 r0, r1;
      asm("v_cvt_pk_bf16_f32 %0, %1, %2" : "=v"(r0) : "v"(pp0[2 * e]), "v"(pp0[2 * e + 1]));
      asm("v_cvt_pk_bf16_f32 %0, %1, %2" : "=v"(r1) : "v"(pp1[2 * e]), "v"(pp1[2 * e + 1]));
      pa0.w[e] = r0;
      pa1.w[e] = r1;
    }

    __builtin_amdgcn_s_setprio(1);
#pragma unroll
    for (int ct = 0; ct < 4; ++ct) {
      oacc[ct] = __builtin_amdgcn_mfma_f32_32x32x16_bf16(pa0.v, vf[ct * 2 + 0], oacc[ct], 0, 0, 0);
      oacc[ct] = __builtin_amdgcn_mfma_f32_32x32x16_bf16(pa1.v, vf[ct * 2 + 1], oacc[ct], 0, 0, 0);
    }
    __builtin_amdgcn_s_setprio(0);
  }

  lacc += __shfl_xor(lacc, 32);

  __syncthreads();
  if (wave == 0) {
#pragma unroll
    for (int ct = 0; ct < 4; ++ct)
#pragma unroll
      for (int reg = 0; reg < 16; ++reg)
        Obuf[SIG(reg, half)][ct * 32 + lm] = oacc[ct][reg];
    if (half == 0) lbuf[lm] = lacc;
  }
  __syncthreads();
  if (wave != 0) {
#pragma unroll
    for (int ct = 0; ct < 4; ++ct)
#pragma unroll
      for (int reg = 0; reg < 16; ++reg)
        atomicAdd(&Obuf[SIG(reg, half)][ct * 32 + lm], oacc[ct][reg]);
    if (half == 0) atomicAdd(&lbuf[lm], lacc);
  }
  __syncthreads();

  // normalize + store Of bf16 frag-major; wave w handles ks = w
  {
    const float inv = 1.0f / lbuf[lm];
    u16* ob = Of + (size_t)b * PB + (size_t)nblk * 4096 + half * 256 + lm * 8;
    const int ks = wave;
    float4 va = *(const float4*)&Obuf[lm][ks * 16 + half * 8];
    float4 vb = *(const float4*)&Obuf[lm][ks * 16 + half * 8 + 4];
    uint4 pk = make_uint4(pk2(va.x * inv, va.y * inv), pk2(va.z * inv, va.w * inv),
                          pk2(vb.x * inv, vb.y * inv), pk2(vb.z * inv, vb.w * inv));
    *(uint4*)(ob + ks * 512) = pk;
  }
}

// ---------------------------------------------------------------------------
// Kernel 3: MFMA out-projection + BN + residual.
// grid = (NHW/32, B), block = 256 (4 waves).  Wave w: co-tiles {2w, 2w+1}.
// D = W2·O (A=W2 m=co, B=Of col=n); epilogue: *scale[co] + offs[co] + z.
// ---------------------------------------------------------------------------
__global__ __launch_bounds__(256) void outproj_kernel(
    const u16* __restrict__ Of, const float* __restrict__ zz,
    const u16* __restrict__ Wf2, const float* __restrict__ scl,
    const float* __restrict__ offs, float* __restrict__ out)
{
  __shared__ float SC[256], OFS[256];
  const int t = threadIdx.x;
  const int wave = t >> 6, lane = t & 63;
  const int lm = lane & 31, h = lane >> 5;
  const int b = blockIdx.y;
  const int n0 = blockIdx.x * 32;

  SC[t] = scl[t];
  OFS[t] = offs[t];
  __syncthreads();

  s8v of[8];
  {
    const u16* op = Of + (size_t)b * PB + (size_t)blockIdx.x * 4096 + h * 256 + lm * 8;
#pragma unroll
    for (int ks = 0; ks < 8; ++ks) of[ks] = *(const s8v*)(op + ks * 512);
  }

  f16v a0, a1;
#pragma unroll
  for (int r = 0; r < 16; ++r) { a0[r] = 0.f; a1[r] = 0.f; }

  const u16* w2a = Wf2 + (wave * 2 + 0) * 8192 + h * 256 + lm * 8;
  const u16* w2b = Wf2 + (wave * 2 + 1) * 8192 + h * 256 + lm * 8;
#pragma unroll
  for (int ks = 0; ks < 8; ++ks) {
    s8v wa = *(const s8v*)(w2a + ks * 512);
    s8v wb = *(const s8v*)(w2b + ks * 512);
    a0 = __builtin_amdgcn_mfma_f32_32x32x16_bf16(wa, of[ks], a0, 0, 0, 0);
    a1 = __builtin_amdgcn_mfma_f32_32x32x16_bf16(wb, of[ks], a1, 0, 0, 0);
  }

#pragma unroll
  for (int cti = 0; cti < 2; ++cti) {
    const int ct = wave * 2 + cti;
    const f16v& ac = cti ? a1 : a0;
#pragma unroll
    for (int reg = 0; reg < 16; ++reg) {
      const int co = ct * 32 + SIG(reg, h);
      const size_t idx = ((size_t)(b * CIN + co)) * NHW + n0 + lm;
      out[idx] = ac[reg] * SC[co] + OFS[co] + zz[idx];
    }
  }
}

// ---------------------------------------------------------------------------
extern "C" void kernel_launch(void* const* d_in, const int* in_sizes, int n_in,
                              void* d_out, int out_size, void* d_ws, size_t ws_size,
                              hipStream_t stream) {
  const float* x  = (const float*)d_in[0];
  const float* y  = (const float*)d_in[1];
  const float* z  = (const float*)d_in[2];
  const float* tw = (const float*)d_in[3];
  const float* tb = (const float*)d_in[4];
  const float* pw = (const float*)d_in[5];
  const float* pb = (const float*)d_in[6];
  const float* gw = (const float*)d_in[7];
  const float* gb = (const float*)d_in[8];
  const float* ww = (const float*)d_in[9];
  const float* wb = (const float*)d_in[10];
  const float* bn_g = (const float*)d_in[11];
  const float* bn_b = (const float*)d_in[12];
  const float* bn_m = (const float*)d_in[13];
  const float* bn_v = (const float*)d_in[14];

  const size_t B = 4;
  const size_t qkv = B * PB;  // 2,097,152 u16
  char* ws = (char*)d_ws;
  u16* Qf = (u16*)ws;
  u16* Kf = Qf + qkv;
  u16* Vf = Kf + qkv;
  u16* Of = Vf + qkv;
  u16* Wf = Of + qkv;          // 3*32768
  u16* Wf2 = Wf + 3 * 32768;   // 8*8192 = 65536
  float* scl  = (float*)(Wf2 + 65536);
  float* offs = scl + 256;

  float* out = (float*)d_out;

  wprep_kernel<<<21, 256, 0, stream>>>(tw, pw, gw, ww, wb, bn_g, bn_b, bn_m, bn_v,
                                       Wf, Wf2, scl, offs);
  proj_kernel<<<dim3(NHW / 64, B, 3), 256, 0, stream>>>(
      x, y, z, Wf, tb, pb, gb, Qf, Kf, Vf);
  attn_kernel<<<dim3((NHW / 32) * 4), 512, 0, stream>>>(Qf, Kf, Vf, Of);
  outproj_kernel<<<dim3(NHW / 32, B), 256, 0, stream>>>(
      Of, z, Wf2, scl, offs, out);
}

// Round 4
// 208.345 us; speedup vs baseline: 2.4101x; 2.4101x over previous
//
#include <hip/hip_runtime.h>

typedef unsigned short u16;
typedef unsigned int u32;
typedef short s8v __attribute__((ext_vector_type(8)));    // 8 bf16 (4 VGPRs)
typedef float f16v __attribute__((ext_vector_type(16)));  // 32x32 mfma acc

#define NHW 4096   // H*W
#define CIN 256    // C
#define CID 128    // CI (inter channels)
#define PB  524288 // per-batch frag elems (NHW*CID)
#define RLN2 1.4426950408889634f

__device__ __forceinline__ u16 f2bf(float f) {
  union { float f; u32 u; } v; v.f = f;
  u32 r = v.u + 0x7fffu + ((v.u >> 16) & 1u);
  return (u16)(r >> 16);
}
__device__ __forceinline__ u32 pk2(float a, float b) {
  return (u32)f2bf(a) | ((u32)f2bf(b) << 16);
}
__device__ __forceinline__ int SIG(int reg, int h) {
  return (reg & 3) + 8 * (reg >> 2) + 4 * h;
}
// hardware 2^x (v_exp_f32); avoids glibc __exp2f macro collision
__device__ __forceinline__ float hw_exp2(float x) {
  float r;
  asm("v_exp_f32 %0, %1" : "=v"(r) : "v"(x));
  return r;
}

// Frag-major layouts (per batch):
//  Qf/Kf[nblk128][ct4][hp2][lm32][r16] : value D(n = nblk*32+lm, ci-label(ct,hp,r))
//  Vf[mblk128][ct4][ks2][hp2][lm32][j8]: V[m = mblk*32 + ks*16 + SIG(j,hp)][ci=ct*32+lm]
//  Of[nblk128][ks8][h2][lm32][j8]      : O[n=nblk*32+lm][ci = ks*16+h*8+j]  (plain)
//  Wf [p3][ct4][ksg16][h2][lm32][j8]   : W[ci=ct*32+lm][c = ksg*16+h*8+j] bf16
//  Wf2[ct8][ks8][h2][lm32][j8]         : W2[co=ct*32+lm][ci = ks*16+h*8+j] bf16
// NOTE: theta (p=0) weights+bias are pre-scaled by 1/ln2 so attn uses exp2
// directly (softmax exactly invariant: 2^(S/ln2) = e^S).

// ---------------------------------------------------------------------------
// Kernel 0: weight prep (bf16 frag-major) + BN fold.  grid=21, block=256.
// ---------------------------------------------------------------------------
__global__ __launch_bounds__(256) void wprep_kernel(
    const float* __restrict__ tw, const float* __restrict__ pw, const float* __restrict__ gw,
    const float* __restrict__ ww, const float* __restrict__ wb,
    const float* __restrict__ bg, const float* __restrict__ bb,
    const float* __restrict__ bm, const float* __restrict__ bv,
    u16* __restrict__ Wf, u16* __restrict__ Wf2,
    float* __restrict__ scl, float* __restrict__ offs)
{
  const int bid = blockIdx.x, t = threadIdx.x;
  const int lm = t & 31, h = (t >> 5) & 1, g4 = t >> 6;
  if (bid < 12) {
    const int p = bid >> 2, ct = bid & 3;
    const float* W = (p == 0) ? tw : (p == 1) ? pw : gw;
    const float wsc = (p == 0) ? RLN2 : 1.0f;  // fold 1/ln2 into theta
#pragma unroll
    for (int q = 0; q < 4; ++q) {
      const int ksg = g4 * 4 + q;
      const float* src = W + (size_t)(ct * 32 + lm) * 256 + ksg * 16 + h * 8;
      u32 pk[4];
#pragma unroll
      for (int e = 0; e < 4; ++e) pk[e] = pk2(src[2 * e] * wsc, src[2 * e + 1] * wsc);
      *(uint4*)(Wf + p * 32768 + ct * 8192 + ksg * 512 + h * 256 + lm * 8) =
          make_uint4(pk[0], pk[1], pk[2], pk[3]);
    }
  } else if (bid < 20) {
    const int ct = bid - 12;
#pragma unroll
    for (int q = 0; q < 2; ++q) {
      const int ks = g4 * 2 + q;
      const float* src = ww + (size_t)(ct * 32 + lm) * 128 + ks * 16 + h * 8;
      u32 pk[4];
#pragma unroll
      for (int e = 0; e < 4; ++e) pk[e] = pk2(src[2 * e], src[2 * e + 1]);
      *(uint4*)(Wf2 + ct * 8192 + ks * 512 + h * 256 + lm * 8) =
          make_uint4(pk[0], pk[1], pk[2], pk[3]);
    }
  } else {
    float inv = bg[t] * __frsqrt_rn(bv[t] + 1e-5f);
    scl[t] = inv;
    offs[t] = (wb[t] - bm[t]) * inv + bb[t];
  }
}

// ---------------------------------------------------------------------------
// Kernel 1: MFMA projections.  grid=(NHW/64, B, 3), block=256 (4 waves).
// ---------------------------------------------------------------------------
__global__ __launch_bounds__(256) void proj_kernel(
    const float* __restrict__ x, const float* __restrict__ y, const float* __restrict__ zz,
    const u16* __restrict__ Wf,
    const float* __restrict__ tb, const float* __restrict__ pb, const float* __restrict__ gb,
    u16* __restrict__ Qf, u16* __restrict__ Kf, u16* __restrict__ Vf)
{
  __shared__ __align__(16) u16 Xs[64 * 64];
  __shared__ float Bs[128];
  const int t = threadIdx.x;
  const int b = blockIdx.y, p = blockIdx.z;
  const int n0 = blockIdx.x * 64;
  const float* in  = (p == 0) ? x  : (p == 1) ? y  : zz;
  const float* Bv  = (p == 0) ? tb : (p == 1) ? pb : gb;
  u16*         out = (p == 0) ? Qf : (p == 1) ? Kf : Vf;
  const u16* Wfp = Wf + p * 32768;
  const float bscale = (p == 0) ? RLN2 : 1.0f;  // theta bias also scaled

  const int wave = t >> 6, lane = t & 63;
  const int lm = lane & 31, h = lane >> 5;
  const int nt = wave & 1, ctp = wave >> 1;
  const int cp = t >> 3, noct = t & 7;   // staging map: c-pair, n-oct

  if (t < 128) Bs[t] = Bv[t];

  u32* Xd = (u32*)Xs;
  const int nn = nt * 32 + lm;
  const int rmask = ((nn >> 3) & 7) << 2;

  f16v a0, a1;
#pragma unroll
  for (int r = 0; r < 16; ++r) { a0[r] = 0.f; a1[r] = 0.f; }

  float4 xr[4];
  {
    const float* basep = in + ((size_t)(b * CIN) + 2 * cp) * NHW + n0;
    xr[0] = *(const float4*)(basep + noct * 4);
    xr[1] = *(const float4*)(basep + 32 + noct * 4);
    xr[2] = *(const float4*)(basep + NHW + noct * 4);
    xr[3] = *(const float4*)(basep + NHW + 32 + noct * 4);
  }

  for (int ch = 0; ch < 4; ++ch) {
    __syncthreads();  // previous chunk consumed
    {
      const float* xa = (const float*)&xr[0];
      const float* xb = (const float*)&xr[1];
      const float* xc = (const float*)&xr[2];
      const float* xd = (const float*)&xr[3];
#pragma unroll
      for (int i = 0; i < 4; ++i) {
        int n1 = noct * 4 + i, n2 = n1 + 32;
        Xd[n1 * 32 + (cp ^ (((n1 >> 3) & 7) << 2))] = pk2(xa[i], xc[i]);
        Xd[n2 * 32 + (cp ^ (((n2 >> 3) & 7) << 2))] = pk2(xb[i], xd[i]);
      }
    }
    __syncthreads();
    if (ch < 3) {
      const float* basep = in + ((size_t)(b * CIN) + (ch + 1) * 64 + 2 * cp) * NHW + n0;
      xr[0] = *(const float4*)(basep + noct * 4);
      xr[1] = *(const float4*)(basep + 32 + noct * 4);
      xr[2] = *(const float4*)(basep + NHW + noct * 4);
      xr[3] = *(const float4*)(basep + NHW + 32 + noct * 4);
    }
    if (p < 2) {
#pragma unroll
      for (int ks = 0; ks < 4; ++ks) {
        s8v xf = *(const s8v*)(Xd + nn * 32 + ((ks * 8 + h * 4) ^ rmask));
        s8v w0 = *(const s8v*)(Wfp + (ctp * 2 + 0) * 8192 + (ch * 4 + ks) * 512 + h * 256 + lm * 8);
        s8v w1 = *(const s8v*)(Wfp + (ctp * 2 + 1) * 8192 + (ch * 4 + ks) * 512 + h * 256 + lm * 8);
        a0 = __builtin_amdgcn_mfma_f32_32x32x16_bf16(w0, xf, a0, 0, 0, 0);
        a1 = __builtin_amdgcn_mfma_f32_32x32x16_bf16(w1, xf, a1, 0, 0, 0);
      }
    } else {
#pragma unroll
      for (int ks = 0; ks < 4; ++ks) {
        s8v xf = *(const s8v*)(Xd + nn * 32 + ((ks * 8 + h * 4) ^ rmask));
        s8v w0 = *(const s8v*)(Wfp + (ctp * 2 + 0) * 8192 + (ch * 4 + ks) * 512 + h * 256 + lm * 8);
        s8v w1 = *(const s8v*)(Wfp + (ctp * 2 + 1) * 8192 + (ch * 4 + ks) * 512 + h * 256 + lm * 8);
        a0 = __builtin_amdgcn_mfma_f32_32x32x16_bf16(xf, w0, a0, 0, 0, 0);
        a1 = __builtin_amdgcn_mfma_f32_32x32x16_bf16(xf, w1, a1, 0, 0, 0);
      }
    }
  }

  // epilogue
  const size_t nblk = (size_t)blockIdx.x * 2 + nt;
  if (p < 2) {
#pragma unroll
    for (int cti = 0; cti < 2; ++cti) {
      const int ct = ctp * 2 + cti;
      const f16v& ac = cti ? a1 : a0;
      float v[16];
#pragma unroll
      for (int reg = 0; reg < 16; ++reg)
        v[reg] = ac[reg] + Bs[ct * 32 + SIG(reg, h)] * bscale;
      u32 pk[8];
#pragma unroll
      for (int e = 0; e < 8; ++e) pk[e] = pk2(v[2 * e], v[2 * e + 1]);
      u16* dst = out + (size_t)b * PB + nblk * 4096 + ct * 1024 + h * 512 + lm * 16;
      ((uint4*)dst)[0] = make_uint4(pk[0], pk[1], pk[2], pk[3]);
      ((uint4*)dst)[1] = make_uint4(pk[4], pk[5], pk[6], pk[7]);
    }
  } else {
#pragma unroll
    for (int cti = 0; cti < 2; ++cti) {
      const int ct = ctp * 2 + cti;
      const f16v& ac = cti ? a1 : a0;
      const float bias = Bs[ct * 32 + lm];
      u32 pk[8];
#pragma unroll
      for (int e = 0; e < 8; ++e) pk[e] = pk2(ac[2 * e] + bias, ac[2 * e + 1] + bias);
      u16* dst = out + (size_t)b * PB + nblk * 4096 + ct * 1024 + h * 256 + lm * 8;
      *(uint4*)dst         = make_uint4(pk[0], pk[1], pk[2], pk[3]);
      *(uint4*)(dst + 512) = make_uint4(pk[4], pk[5], pk[6], pk[7]);
    }
  }
}

// ---------------------------------------------------------------------------
// Kernel 2: MFMA flash attention. grid = 512 (XCD-swizzled), block = 256
// (4 waves, wave w: m-quarter). Q staged in XOR-swizzled LDS (block-shared),
// freeing 32 VGPRs for kfA/kfB double-buffer with ~2-tile prefetch distance;
// jt unrolled x2 so two tile-pipelines interleave. Reg budget ~236 <= 256
// (2 waves/SIMD preserved -- NO launch_bounds change, round-2 spill lesson).
// ---------------------------------------------------------------------------
__global__ __launch_bounds__(256, 2) void attn_kernel(
    const u16* __restrict__ Qf, const u16* __restrict__ Kf,
    const u16* __restrict__ Vf, u16* __restrict__ Of)
{
  __shared__ __align__(16) u16 Qs[4096];            // 8KB swizzled Q tile
  __shared__ __align__(16) float Obuf[32][132];
  __shared__ float lbuf[32];
  const int t = threadIdx.x;
  const int wave = t >> 6, lane = t & 63;
  const int lm = lane & 31, half = lane >> 5;

  // XCD-aware decode: bijective over (b, nblk). 2 XCDs per batch.
  const int lin = blockIdx.x;
  const int xcd = lin & 7;
  const int b = xcd >> 1;
  const int nblk = ((xcd & 1) << 6) + (lin >> 3);

  // cooperative Q stage, XOR-swizzled: slot s' = s ^ ((s>>1)&7) within 1KB
  {
    const u16* qsrc = Qf + (size_t)b * PB + (size_t)nblk * 4096;
#pragma unroll
    for (int pass = 0; pass < 2; ++pass) {
      const int e = pass * 2048 + t * 8;
      uint4 v = *(const uint4*)(qsrc + e);
      const int byte = e * 2;
      const int swz = ((t >> 1) & 7) << 4;
      *(uint4*)((char*)Qs + (byte & ~1023) + ((byte & 1023) ^ swz)) = v;
    }
  }
  __syncthreads();

  // per-lane swizzled Q base (read pattern matches write swizzle)
  const char* Qb = (const char*)Qs + ((lm * 32 + half * 16) ^ ((lm & 7) << 4));
  const u16* Kb = Kf + (size_t)b * PB + lm * 16 + half * 8;
  const u16* Vb = Vf + (size_t)b * PB + half * 256 + lm * 8;
  const int mstart = wave * 1024;

  f16v oacc[4];
#pragma unroll
  for (int c = 0; c < 4; ++c)
#pragma unroll
    for (int r = 0; r < 16; ++r) oacc[c][r] = 0.f;
  float lacc0 = 0.f, lacc1 = 0.f;

  s8v kfA[8], kfB[8], vf[8];
  {
    const u16* kp = Kb + (size_t)mstart * 128;
#pragma unroll
    for (int ks = 0; ks < 8; ++ks) kfA[ks] = *(const s8v*)(kp + ks * 512);
#pragma unroll
    for (int ks = 0; ks < 8; ++ks) kfB[ks] = *(const s8v*)(kp + 4096 + ks * 512);
  }
  {
    const u16* vp = Vb + (size_t)mstart * 128;
#pragma unroll
    for (int ct = 0; ct < 4; ++ct)
#pragma unroll
      for (int ks = 0; ks < 2; ++ks)
        vf[ct * 2 + ks] = *(const s8v*)(vp + ct * 1024 + ks * 512);
  }

#define QK_TILE(KF)                                                            \
  {                                                                            \
    __builtin_amdgcn_s_setprio(1);                                             \
    _Pragma("unroll")                                                          \
    for (int ks = 0; ks < 4; ++ks) {                                           \
      s8v q0 = *(const s8v*)(Qb + ks * 1024);                                  \
      s8v q1 = *(const s8v*)(Qb + (ks + 4) * 1024);                            \
      s0 = __builtin_amdgcn_mfma_f32_32x32x16_bf16(KF[ks], q0, s0, 0, 0, 0);   \
      s1 = __builtin_amdgcn_mfma_f32_32x32x16_bf16(KF[ks + 4], q1, s1, 0, 0, 0);\
    }                                                                          \
    __builtin_amdgcn_s_setprio(0);                                             \
  }

#define KLOAD(KF, M)                                                           \
  {                                                                            \
    const u16* kp = Kb + (size_t)(M) * 128;                                    \
    _Pragma("unroll")                                                          \
    for (int ks = 0; ks < 8; ++ks) KF[ks] = *(const s8v*)(kp + ks * 512);      \
  }

#define VLOAD(M)                                                               \
  {                                                                            \
    const u16* vp = Vb + (size_t)(M) * 128;                                    \
    _Pragma("unroll")                                                          \
    for (int ct = 0; ct < 4; ++ct)                                             \
      _Pragma("unroll")                                                        \
      for (int ks = 0; ks < 2; ++ks)                                           \
        vf[ct * 2 + ks] = *(const s8v*)(vp + ct * 1024 + ks * 512);            \
  }

#define EXP_PV()                                                               \
  {                                                                            \
    float pp0[8], pp1[8];                                                      \
    _Pragma("unroll")                                                          \
    for (int j = 0; j < 8; ++j) {                                              \
      float p0 = hw_exp2(s0[j] + s1[j]);                                       \
      float p1 = hw_exp2(s0[8 + j] + s1[8 + j]);                               \
      if (j & 1) lacc1 += p0 + p1; else lacc0 += p0 + p1;                      \
      pp0[j] = p0; pp1[j] = p1;                                                \
    }                                                                          \
    union { s8v v; u32 w[4]; } pa0, pa1;                                       \
    _Pragma("unroll")                                                          \
    for (int e = 0; e < 4; ++e) {                                              \
      u32 r0, r1;                                                              \
      asm("v_cvt_pk_bf16_f32 %0, %1, %2" : "=v"(r0) : "v"(pp0[2*e]), "v"(pp0[2*e+1])); \
      asm("v_cvt_pk_bf16_f32 %0, %1, %2" : "=v"(r1) : "v"(pp1[2*e]), "v"(pp1[2*e+1])); \
      pa0.w[e] = r0; pa1.w[e] = r1;                                            \
    }                                                                          \
    __builtin_amdgcn_s_setprio(1);                                             \
    _Pragma("unroll")                                                          \
    for (int ct = 0; ct < 4; ++ct) {                                           \
      oacc[ct] = __builtin_amdgcn_mfma_f32_32x32x16_bf16(pa0.v, vf[ct*2+0], oacc[ct], 0, 0, 0); \
      oacc[ct] = __builtin_amdgcn_mfma_f32_32x32x16_bf16(pa1.v, vf[ct*2+1], oacc[ct], 0, 0, 0); \
    }                                                                          \
    __builtin_amdgcn_s_setprio(0);                                             \
  }

  for (int tt = 0; tt < 16; ++tt) {
    const int mA = mstart + tt * 64;
    // ---- tile A (kfA; vf holds V(mA)) ----
    f16v s0, s1;
#pragma unroll
    for (int r = 0; r < 16; ++r) { s0[r] = 0.f; s1[r] = 0.f; }
    QK_TILE(kfA)
    KLOAD(kfA, mA + 64)      // next A tile: ~2 tile-periods ahead of use
    EXP_PV()
    VLOAD(mA + 32)           // V for tile B
    // ---- tile B (kfB) ----
#pragma unroll
    for (int r = 0; r < 16; ++r) { s0[r] = 0.f; s1[r] = 0.f; }
    QK_TILE(kfB)
    KLOAD(kfB, mA + 96)      // next B tile
    EXP_PV()
    VLOAD(mA + 64)           // V for next A tile
  }
#undef QK_TILE
#undef KLOAD
#undef VLOAD
#undef EXP_PV

  float lacc = lacc0 + lacc1;
  lacc += __shfl_xor(lacc, 32);

  __syncthreads();
  if (wave == 0) {
#pragma unroll
    for (int ct = 0; ct < 4; ++ct)
#pragma unroll
      for (int reg = 0; reg < 16; ++reg)
        Obuf[SIG(reg, half)][ct * 32 + lm] = oacc[ct][reg];
    if (half == 0) lbuf[lm] = lacc;
  }
  __syncthreads();
  if (wave != 0) {
#pragma unroll
    for (int ct = 0; ct < 4; ++ct)
#pragma unroll
      for (int reg = 0; reg < 16; ++reg)
        atomicAdd(&Obuf[SIG(reg, half)][ct * 32 + lm], oacc[ct][reg]);
    if (half == 0) atomicAdd(&lbuf[lm], lacc);
  }
  __syncthreads();

  // normalize + store Of bf16 frag-major; wave w: ks-pair {2w, 2w+1}
  {
    const float inv = 1.0f / lbuf[lm];
    u16* ob = Of + (size_t)b * PB + (size_t)nblk * 4096 + half * 256 + lm * 8;
#pragma unroll
    for (int kss = 0; kss < 2; ++kss) {
      const int ks = wave * 2 + kss;
      float4 va = *(const float4*)&Obuf[lm][ks * 16 + half * 8];
      float4 vb = *(const float4*)&Obuf[lm][ks * 16 + half * 8 + 4];
      uint4 pk = make_uint4(pk2(va.x * inv, va.y * inv), pk2(va.z * inv, va.w * inv),
                            pk2(vb.x * inv, vb.y * inv), pk2(vb.z * inv, vb.w * inv));
      *(uint4*)(ob + ks * 512) = pk;
    }
  }
}

// ---------------------------------------------------------------------------
// Kernel 3: MFMA out-projection + BN + residual.
// ---------------------------------------------------------------------------
__global__ __launch_bounds__(256) void outproj_kernel(
    const u16* __restrict__ Of, const float* __restrict__ zz,
    const u16* __restrict__ Wf2, const float* __restrict__ scl,
    const float* __restrict__ offs, float* __restrict__ out)
{
  __shared__ float SC[256], OFS[256];
  const int t = threadIdx.x;
  const int wave = t >> 6, lane = t & 63;
  const int lm = lane & 31, h = lane >> 5;
  const int b = blockIdx.y;
  const int n0 = blockIdx.x * 32;

  SC[t] = scl[t];
  OFS[t] = offs[t];
  __syncthreads();

  s8v of[8];
  {
    const u16* op = Of + (size_t)b * PB + (size_t)blockIdx.x * 4096 + h * 256 + lm * 8;
#pragma unroll
    for (int ks = 0; ks < 8; ++ks) of[ks] = *(const s8v*)(op + ks * 512);
  }

  f16v a0, a1;
#pragma unroll
  for (int r = 0; r < 16; ++r) { a0[r] = 0.f; a1[r] = 0.f; }

  const u16* w2a = Wf2 + (wave * 2 + 0) * 8192 + h * 256 + lm * 8;
  const u16* w2b = Wf2 + (wave * 2 + 1) * 8192 + h * 256 + lm * 8;
#pragma unroll
  for (int ks = 0; ks < 8; ++ks) {
    s8v wa = *(const s8v*)(w2a + ks * 512);
    s8v wb = *(const s8v*)(w2b + ks * 512);
    a0 = __builtin_amdgcn_mfma_f32_32x32x16_bf16(wa, of[ks], a0, 0, 0, 0);
    a1 = __builtin_amdgcn_mfma_f32_32x32x16_bf16(wb, of[ks], a1, 0, 0, 0);
  }

#pragma unroll
  for (int cti = 0; cti < 2; ++cti) {
    const int ct = wave * 2 + cti;
    const f16v& ac = cti ? a1 : a0;
#pragma unroll
    for (int reg = 0; reg < 16; ++reg) {
      const int co = ct * 32 + SIG(reg, h);
      const size_t idx = ((size_t)(b * CIN + co)) * NHW + n0 + lm;
      out[idx] = ac[reg] * SC[co] + OFS[co] + zz[idx];
    }
  }
}

// ---------------------------------------------------------------------------
extern "C" void kernel_launch(void* const* d_in, const int* in_sizes, int n_in,
                              void* d_out, int out_size, void* d_ws, size_t ws_size,
                              hipStream_t stream) {
  const float* x  = (const float*)d_in[0];
  const float* y  = (const float*)d_in[1];
  const float* z  = (const float*)d_in[2];
  const float* tw = (const float*)d_in[3];
  const float* tb = (const float*)d_in[4];
  const float* pw = (const float*)d_in[5];
  const float* pb = (const float*)d_in[6];
  const float* gw = (const float*)d_in[7];
  const float* gb = (const float*)d_in[8];
  const float* ww = (const float*)d_in[9];
  const float* wb = (const float*)d_in[10];
  const float* bn_g = (const float*)d_in[11];
  const float* bn_b = (const float*)d_in[12];
  const float* bn_m = (const float*)d_in[13];
  const float* bn_v = (const float*)d_in[14];

  const size_t B = 4;
  const size_t qkv = B * PB;  // 2,097,152 u16
  char* ws = (char*)d_ws;
  u16* Qf = (u16*)ws;
  u16* Kf = Qf + qkv;
  u16* Vf = Kf + qkv;
  u16* Of = Vf + qkv;
  u16* Wf = Of + qkv;          // 3*32768
  u16* Wf2 = Wf + 3 * 32768;   // 8*8192 = 65536
  float* scl  = (float*)(Wf2 + 65536);
  float* offs = scl + 256;

  float* out = (float*)d_out;

  wprep_kernel<<<21, 256, 0, stream>>>(tw, pw, gw, ww, wb, bn_g, bn_b, bn_m, bn_v,
                                       Wf, Wf2, scl, offs);
  proj_kernel<<<dim3(NHW / 64, B, 3), 256, 0, stream>>>(
      x, y, z, Wf, tb, pb, gb, Qf, Kf, Vf);
  attn_kernel<<<dim3((NHW / 32) * 4), 256, 0, stream>>>(Qf, Kf, Vf, Of);
  outproj_kernel<<<dim3(NHW / 32, B), 256, 0, stream>>>(
      Of, z, Wf2, scl, offs, out);
}

// Round 5
// 186.593 us; speedup vs baseline: 2.6910x; 1.1166x over previous
//
#include <hip/hip_runtime.h>

typedef unsigned short u16;
typedef unsigned int u32;
typedef short s8v __attribute__((ext_vector_type(8)));    // 8 bf16 (4 VGPRs)
typedef float f16v __attribute__((ext_vector_type(16)));  // 32x32 mfma acc

#define NHW 4096   // H*W
#define CIN 256    // C
#define CID 128    // CI (inter channels)
#define PB  524288 // per-batch frag elems (NHW*CID)
#define RLN2 1.4426950408889634f

__device__ __forceinline__ u16 f2bf(float f) {
  union { float f; u32 u; } v; v.f = f;
  u32 r = v.u + 0x7fffu + ((v.u >> 16) & 1u);
  return (u16)(r >> 16);
}
__device__ __forceinline__ u32 pk2(float a, float b) {
  return (u32)f2bf(a) | ((u32)f2bf(b) << 16);
}
__device__ __forceinline__ int SIG(int reg, int h) {
  return (reg & 3) + 8 * (reg >> 2) + 4 * h;
}
// hardware 2^x (v_exp_f32); avoids glibc __exp2f macro collision
__device__ __forceinline__ float hw_exp2(float x) {
  float r;
  asm("v_exp_f32 %0, %1" : "=v"(r) : "v"(x));
  return r;
}

// Frag-major layouts (per batch):
//  Qf/Kf[nblk128][ct4][hp2][lm32][r16] : value D(n = nblk*32+lm, ci-label(ct,hp,r))
//  Vf[mblk128][ct4][ks2][hp2][lm32][j8]: V[m = mblk*32 + ks*16 + SIG(j,hp)][ci=ct*32+lm]
//  Wf [p3][ct4][ksg16][h2][lm32][j8]   : W[ci=ct*32+lm][c = ksg*16+h*8+j] bf16
//  Wf2[ct8][ks8][h2][lm32][j8]         : W2[co=ct*32+lm][ci = ks*16+h*8+j] bf16
// NOTE: theta (p=0) weights+bias are pre-scaled by 1/ln2 so attn uses exp2
// directly (softmax exactly invariant: 2^(S/ln2) = e^S).
// outproj is FUSED into attn's epilogue (O tile already complete in LDS).

// ---------------------------------------------------------------------------
// Kernel 0: weight prep (bf16 frag-major) + BN fold.  grid=21, block=256.
// ---------------------------------------------------------------------------
__global__ __launch_bounds__(256) void wprep_kernel(
    const float* __restrict__ tw, const float* __restrict__ pw, const float* __restrict__ gw,
    const float* __restrict__ ww, const float* __restrict__ wb,
    const float* __restrict__ bg, const float* __restrict__ bb,
    const float* __restrict__ bm, const float* __restrict__ bv,
    u16* __restrict__ Wf, u16* __restrict__ Wf2,
    float* __restrict__ scl, float* __restrict__ offs)
{
  const int bid = blockIdx.x, t = threadIdx.x;
  const int lm = t & 31, h = (t >> 5) & 1, g4 = t >> 6;
  if (bid < 12) {
    const int p = bid >> 2, ct = bid & 3;
    const float* W = (p == 0) ? tw : (p == 1) ? pw : gw;
    const float wsc = (p == 0) ? RLN2 : 1.0f;  // fold 1/ln2 into theta
#pragma unroll
    for (int q = 0; q < 4; ++q) {
      const int ksg = g4 * 4 + q;
      const float* src = W + (size_t)(ct * 32 + lm) * 256 + ksg * 16 + h * 8;
      u32 pk[4];
#pragma unroll
      for (int e = 0; e < 4; ++e) pk[e] = pk2(src[2 * e] * wsc, src[2 * e + 1] * wsc);
      *(uint4*)(Wf + p * 32768 + ct * 8192 + ksg * 512 + h * 256 + lm * 8) =
          make_uint4(pk[0], pk[1], pk[2], pk[3]);
    }
  } else if (bid < 20) {
    const int ct = bid - 12;
#pragma unroll
    for (int q = 0; q < 2; ++q) {
      const int ks = g4 * 2 + q;
      const float* src = ww + (size_t)(ct * 32 + lm) * 128 + ks * 16 + h * 8;
      u32 pk[4];
#pragma unroll
      for (int e = 0; e < 4; ++e) pk[e] = pk2(src[2 * e], src[2 * e + 1]);
      *(uint4*)(Wf2 + ct * 8192 + ks * 512 + h * 256 + lm * 8) =
          make_uint4(pk[0], pk[1], pk[2], pk[3]);
    }
  } else {
    float inv = bg[t] * __frsqrt_rn(bv[t] + 1e-5f);
    scl[t] = inv;
    offs[t] = (wb[t] - bm[t]) * inv + bb[t];
  }
}

// ---------------------------------------------------------------------------
// Kernel 1: MFMA projections.  grid=(NHW/64, B, 3), block=256 (4 waves).
// ---------------------------------------------------------------------------
__global__ __launch_bounds__(256) void proj_kernel(
    const float* __restrict__ x, const float* __restrict__ y, const float* __restrict__ zz,
    const u16* __restrict__ Wf,
    const float* __restrict__ tb, const float* __restrict__ pb, const float* __restrict__ gb,
    u16* __restrict__ Qf, u16* __restrict__ Kf, u16* __restrict__ Vf)
{
  __shared__ __align__(16) u16 Xs[64 * 64];
  __shared__ float Bs[128];
  const int t = threadIdx.x;
  const int b = blockIdx.y, p = blockIdx.z;
  const int n0 = blockIdx.x * 64;
  const float* in  = (p == 0) ? x  : (p == 1) ? y  : zz;
  const float* Bv  = (p == 0) ? tb : (p == 1) ? pb : gb;
  u16*         out = (p == 0) ? Qf : (p == 1) ? Kf : Vf;
  const u16* Wfp = Wf + p * 32768;
  const float bscale = (p == 0) ? RLN2 : 1.0f;  // theta bias also scaled

  const int wave = t >> 6, lane = t & 63;
  const int lm = lane & 31, h = lane >> 5;
  const int nt = wave & 1, ctp = wave >> 1;
  const int cp = t >> 3, noct = t & 7;   // staging map: c-pair, n-oct

  if (t < 128) Bs[t] = Bv[t];

  u32* Xd = (u32*)Xs;
  const int nn = nt * 32 + lm;
  const int rmask = ((nn >> 3) & 7) << 2;

  f16v a0, a1;
#pragma unroll
  for (int r = 0; r < 16; ++r) { a0[r] = 0.f; a1[r] = 0.f; }

  float4 xr[4];
  {
    const float* basep = in + ((size_t)(b * CIN) + 2 * cp) * NHW + n0;
    xr[0] = *(const float4*)(basep + noct * 4);
    xr[1] = *(const float4*)(basep + 32 + noct * 4);
    xr[2] = *(const float4*)(basep + NHW + noct * 4);
    xr[3] = *(const float4*)(basep + NHW + 32 + noct * 4);
  }

  for (int ch = 0; ch < 4; ++ch) {
    __syncthreads();  // previous chunk consumed
    {
      const float* xa = (const float*)&xr[0];
      const float* xb = (const float*)&xr[1];
      const float* xc = (const float*)&xr[2];
      const float* xd = (const float*)&xr[3];
#pragma unroll
      for (int i = 0; i < 4; ++i) {
        int n1 = noct * 4 + i, n2 = n1 + 32;
        Xd[n1 * 32 + (cp ^ (((n1 >> 3) & 7) << 2))] = pk2(xa[i], xc[i]);
        Xd[n2 * 32 + (cp ^ (((n2 >> 3) & 7) << 2))] = pk2(xb[i], xd[i]);
      }
    }
    __syncthreads();
    if (ch < 3) {
      const float* basep = in + ((size_t)(b * CIN) + (ch + 1) * 64 + 2 * cp) * NHW + n0;
      xr[0] = *(const float4*)(basep + noct * 4);
      xr[1] = *(const float4*)(basep + 32 + noct * 4);
      xr[2] = *(const float4*)(basep + NHW + noct * 4);
      xr[3] = *(const float4*)(basep + NHW + 32 + noct * 4);
    }
    if (p < 2) {
#pragma unroll
      for (int ks = 0; ks < 4; ++ks) {
        s8v xf = *(const s8v*)(Xd + nn * 32 + ((ks * 8 + h * 4) ^ rmask));
        s8v w0 = *(const s8v*)(Wfp + (ctp * 2 + 0) * 8192 + (ch * 4 + ks) * 512 + h * 256 + lm * 8);
        s8v w1 = *(const s8v*)(Wfp + (ctp * 2 + 1) * 8192 + (ch * 4 + ks) * 512 + h * 256 + lm * 8);
        a0 = __builtin_amdgcn_mfma_f32_32x32x16_bf16(w0, xf, a0, 0, 0, 0);
        a1 = __builtin_amdgcn_mfma_f32_32x32x16_bf16(w1, xf, a1, 0, 0, 0);
      }
    } else {
#pragma unroll
      for (int ks = 0; ks < 4; ++ks) {
        s8v xf = *(const s8v*)(Xd + nn * 32 + ((ks * 8 + h * 4) ^ rmask));
        s8v w0 = *(const s8v*)(Wfp + (ctp * 2 + 0) * 8192 + (ch * 4 + ks) * 512 + h * 256 + lm * 8);
        s8v w1 = *(const s8v*)(Wfp + (ctp * 2 + 1) * 8192 + (ch * 4 + ks) * 512 + h * 256 + lm * 8);
        a0 = __builtin_amdgcn_mfma_f32_32x32x16_bf16(xf, w0, a0, 0, 0, 0);
        a1 = __builtin_amdgcn_mfma_f32_32x32x16_bf16(xf, w1, a1, 0, 0, 0);
      }
    }
  }

  // epilogue
  const size_t nblk = (size_t)blockIdx.x * 2 + nt;
  if (p < 2) {
#pragma unroll
    for (int cti = 0; cti < 2; ++cti) {
      const int ct = ctp * 2 + cti;
      const f16v& ac = cti ? a1 : a0;
      float v[16];
#pragma unroll
      for (int reg = 0; reg < 16; ++reg)
        v[reg] = ac[reg] + Bs[ct * 32 + SIG(reg, h)] * bscale;
      u32 pk[8];
#pragma unroll
      for (int e = 0; e < 8; ++e) pk[e] = pk2(v[2 * e], v[2 * e + 1]);
      u16* dst = out + (size_t)b * PB + nblk * 4096 + ct * 1024 + h * 512 + lm * 16;
      ((uint4*)dst)[0] = make_uint4(pk[0], pk[1], pk[2], pk[3]);
      ((uint4*)dst)[1] = make_uint4(pk[4], pk[5], pk[6], pk[7]);
    }
  } else {
#pragma unroll
    for (int cti = 0; cti < 2; ++cti) {
      const int ct = ctp * 2 + cti;
      const f16v& ac = cti ? a1 : a0;
      const float bias = Bs[ct * 32 + lm];
      u32 pk[8];
#pragma unroll
      for (int e = 0; e < 8; ++e) pk[e] = pk2(ac[2 * e] + bias, ac[2 * e + 1] + bias);
      u16* dst = out + (size_t)b * PB + nblk * 4096 + ct * 1024 + h * 256 + lm * 8;
      *(uint4*)dst         = make_uint4(pk[0], pk[1], pk[2], pk[3]);
      *(uint4*)(dst + 512) = make_uint4(pk[4], pk[5], pk[6], pk[7]);
    }
  }
}

// ---------------------------------------------------------------------------
// Kernel 2: MFMA flash attention + FUSED out-projection/BN/residual.
// grid = 512 (1-D, XCD-swizzled), block = 256 = 4 waves; wave w: m-quarter.
// Main loop = round-1 schedule (verified 72.6us) + exp2-fold + split lacc.
// Epilogue: O tile (complete in LDS after reduction) is consumed directly by
// the W2 GEMM: per wave 2 co-tiles x 8 ks MFMAs; *scl+offs+z; store f32 out.
// Index math copied verbatim from the verified standalone outproj kernel.
// ---------------------------------------------------------------------------
__global__ __launch_bounds__(256, 2) void attn_kernel(
    const u16* __restrict__ Qf, const u16* __restrict__ Kf,
    const u16* __restrict__ Vf, const u16* __restrict__ Wf2,
    const float* __restrict__ zz, const float* __restrict__ scl,
    const float* __restrict__ offs, float* __restrict__ out)
{
  __shared__ __align__(16) float Obuf[32][133];  // 133: column-read <=2-way
  __shared__ float lbuf[32];
  __shared__ float SC[256], OFS[256];
  const int t = threadIdx.x;
  const int wave = t >> 6, lane = t & 63;
  const int lm = lane & 31, half = lane >> 5;

  SC[t] = scl[t];
  OFS[t] = offs[t];

  // XCD-aware decode: bijective over (b, nblk). 2 XCDs per batch.
  const int lin = blockIdx.x;
  const int xcd = lin & 7;
  const int b = xcd >> 1;
  const int nblk = ((xcd & 1) << 6) + (lin >> 3);

  // Q B-frags (k-label = sigma-relabeled ci; same labels as Kf -> S correct)
  s8v qf[8];
  {
    const u16* qp = Qf + (size_t)b * PB + (size_t)nblk * 4096 + lm * 16 + half * 8;
#pragma unroll
    for (int ks = 0; ks < 8; ++ks) qf[ks] = *(const s8v*)(qp + ks * 512);
  }

  const u16* Kb = Kf + (size_t)b * PB + lm * 16 + half * 8;
  const u16* Vb = Vf + (size_t)b * PB + half * 256 + lm * 8;
  const int mstart = wave * 1024;

  f16v oacc[4];
#pragma unroll
  for (int c = 0; c < 4; ++c)
#pragma unroll
    for (int r = 0; r < 16; ++r) oacc[c][r] = 0.f;
  float lacc0 = 0.f, lacc1 = 0.f;

  s8v kf[8];
  {
    const u16* kp = Kb + (size_t)mstart * 128;
#pragma unroll
    for (int ks = 0; ks < 8; ++ks) kf[ks] = *(const s8v*)(kp + ks * 512);
  }

  for (int jt = 0; jt < 32; ++jt) {
    const int m0 = mstart + jt * 32;

    s8v vf[8];
    {
      const u16* vp = Vb + (size_t)m0 * 128;
#pragma unroll
      for (int ct = 0; ct < 4; ++ct)
#pragma unroll
        for (int ks = 0; ks < 2; ++ks)
          vf[ct * 2 + ks] = *(const s8v*)(vp + ct * 1024 + ks * 512);
    }

    // Two independent 4-deep MFMA chains; merged in the exp2 argument.
    f16v sacc0, sacc1;
#pragma unroll
    for (int r = 0; r < 16; ++r) { sacc0[r] = 0.f; sacc1[r] = 0.f; }
    __builtin_amdgcn_s_setprio(1);
#pragma unroll
    for (int ks = 0; ks < 4; ++ks) {
      sacc0 = __builtin_amdgcn_mfma_f32_32x32x16_bf16(kf[ks], qf[ks], sacc0, 0, 0, 0);
      sacc1 = __builtin_amdgcn_mfma_f32_32x32x16_bf16(kf[ks + 4], qf[ks + 4], sacc1, 0, 0, 0);
    }
    __builtin_amdgcn_s_setprio(0);

    {
      const u16* kp = Kb + (size_t)(m0 + 32) * 128;
#pragma unroll
      for (int ks = 0; ks < 8; ++ks) kf[ks] = *(const s8v*)(kp + ks * 512);
    }

    float pp0[8], pp1[8];
#pragma unroll
    for (int j = 0; j < 8; ++j) {
      float p0 = hw_exp2(sacc0[j] + sacc1[j]);
      float p1 = hw_exp2(sacc0[8 + j] + sacc1[8 + j]);
      if (j & 1) lacc1 += p0 + p1; else lacc0 += p0 + p1;
      pp0[j] = p0; pp1[j] = p1;
    }
    union { s8v v; u32 w[4]; } pa0, pa1;
#pragma unroll
    for (int e = 0; e < 4; ++e) {
      u32 r0, r1;
      asm("v_cvt_pk_bf16_f32 %0, %1, %2" : "=v"(r0) : "v"(pp0[2 * e]), "v"(pp0[2 * e + 1]));
      asm("v_cvt_pk_bf16_f32 %0, %1, %2" : "=v"(r1) : "v"(pp1[2 * e]), "v"(pp1[2 * e + 1]));
      pa0.w[e] = r0;
      pa1.w[e] = r1;
    }

    __builtin_amdgcn_s_setprio(1);
#pragma unroll
    for (int ct = 0; ct < 4; ++ct) {
      oacc[ct] = __builtin_amdgcn_mfma_f32_32x32x16_bf16(pa0.v, vf[ct * 2 + 0], oacc[ct], 0, 0, 0);
      oacc[ct] = __builtin_amdgcn_mfma_f32_32x32x16_bf16(pa1.v, vf[ct * 2 + 1], oacc[ct], 0, 0, 0);
    }
    __builtin_amdgcn_s_setprio(0);
  }

  float lacc = lacc0 + lacc1;
  lacc += __shfl_xor(lacc, 32);

  __syncthreads();
  if (wave == 0) {
#pragma unroll
    for (int ct = 0; ct < 4; ++ct)
#pragma unroll
      for (int reg = 0; reg < 16; ++reg)
        Obuf[SIG(reg, half)][ct * 32 + lm] = oacc[ct][reg];
    if (half == 0) lbuf[lm] = lacc;
  }
  __syncthreads();
  if (wave != 0) {
#pragma unroll
    for (int ct = 0; ct < 4; ++ct)
#pragma unroll
      for (int reg = 0; reg < 16; ++reg)
        atomicAdd(&Obuf[SIG(reg, half)][ct * 32 + lm], oacc[ct][reg]);
    if (half == 0) atomicAdd(&lbuf[lm], lacc);
  }
  __syncthreads();

  // ---- fused out-projection: out = BN(W2 . O) + z -------------------------
  // B-frags: ofr[ks][lane] = O[n=lm][ci=ks*16+half*8+j] * inv  (bf16)
  {
    const float inv = 1.0f / lbuf[lm];
    s8v ofr[8];
#pragma unroll
    for (int ks = 0; ks < 8; ++ks) {
      const float* src = &Obuf[lm][ks * 16 + half * 8];
      union { s8v v; u32 w[4]; } pa;
#pragma unroll
      for (int e = 0; e < 4; ++e) {
        float f0 = src[2 * e] * inv, f1 = src[2 * e + 1] * inv;
        u32 r;
        asm("v_cvt_pk_bf16_f32 %0, %1, %2" : "=v"(r) : "v"(f0), "v"(f1));
        pa.w[e] = r;
      }
      ofr[ks] = pa.v;
    }

    f16v a0, a1;
#pragma unroll
    for (int r = 0; r < 16; ++r) { a0[r] = 0.f; a1[r] = 0.f; }

    const u16* w2a = Wf2 + (wave * 2 + 0) * 8192 + half * 256 + lm * 8;
    const u16* w2b = Wf2 + (wave * 2 + 1) * 8192 + half * 256 + lm * 8;
#pragma unroll
    for (int ks = 0; ks < 8; ++ks) {
      s8v wa = *(const s8v*)(w2a + ks * 512);
      s8v wb = *(const s8v*)(w2b + ks * 512);
      a0 = __builtin_amdgcn_mfma_f32_32x32x16_bf16(wa, ofr[ks], a0, 0, 0, 0);
      a1 = __builtin_amdgcn_mfma_f32_32x32x16_bf16(wb, ofr[ks], a1, 0, 0, 0);
    }

    const int n0 = nblk * 32;
#pragma unroll
    for (int cti = 0; cti < 2; ++cti) {
      const int ct = wave * 2 + cti;
      const f16v& ac = cti ? a1 : a0;
#pragma unroll
      for (int reg = 0; reg < 16; ++reg) {
        const int co = ct * 32 + SIG(reg, half);
        const size_t idx = ((size_t)(b * CIN + co)) * NHW + n0 + lm;
        out[idx] = ac[reg] * SC[co] + OFS[co] + zz[idx];
      }
    }
  }
}

// ---------------------------------------------------------------------------
extern "C" void kernel_launch(void* const* d_in, const int* in_sizes, int n_in,
                              void* d_out, int out_size, void* d_ws, size_t ws_size,
                              hipStream_t stream) {
  const float* x  = (const float*)d_in[0];
  const float* y  = (const float*)d_in[1];
  const float* z  = (const float*)d_in[2];
  const float* tw = (const float*)d_in[3];
  const float* tb = (const float*)d_in[4];
  const float* pw = (const float*)d_in[5];
  const float* pb = (const float*)d_in[6];
  const float* gw = (const float*)d_in[7];
  const float* gb = (const float*)d_in[8];
  const float* ww = (const float*)d_in[9];
  const float* wb = (const float*)d_in[10];
  const float* bn_g = (const float*)d_in[11];
  const float* bn_b = (const float*)d_in[12];
  const float* bn_m = (const float*)d_in[13];
  const float* bn_v = (const float*)d_in[14];

  const size_t B = 4;
  const size_t qkv = B * PB;  // 2,097,152 u16
  char* ws = (char*)d_ws;
  u16* Qf = (u16*)ws;
  u16* Kf = Qf + qkv;
  u16* Vf = Kf + qkv;
  u16* Wf = Vf + qkv;          // 3*32768
  u16* Wf2 = Wf + 3 * 32768;   // 8*8192 = 65536
  float* scl  = (float*)(Wf2 + 65536);
  float* offs = scl + 256;

  float* out = (float*)d_out;

  wprep_kernel<<<21, 256, 0, stream>>>(tw, pw, gw, ww, wb, bn_g, bn_b, bn_m, bn_v,
                                       Wf, Wf2, scl, offs);
  proj_kernel<<<dim3(NHW / 64, B, 3), 256, 0, stream>>>(
      x, y, z, Wf, tb, pb, gb, Qf, Kf, Vf);
  attn_kernel<<<dim3((NHW / 32) * 4), 256, 0, stream>>>(
      Qf, Kf, Vf, Wf2, z, scl, offs, out);
}